// Round 5
// baseline (435.590 us; speedup 1.0000x reference)
//
#include <hip/hip_runtime.h>
#include <math.h>

// ---------------------------------------------------------------------------
// MultiHead_CrossAttention: out = (softmax_heads((y@Wq)·(x@Wkv_k)^T/8) @ Wkv_v) @ Wo
// B=4 L=4096 D=1024 H=16 hd=64.
// R8: 32x32x16 MFMA kept, but LDS stored K-OCTET-MAJOR per ring slot:
//     A[oct][row][8 kcols] (16 B entries). A 32x32 frag read = each lane
//     reads one complete contiguous 16B entry; the wave covers contiguous
//     512B blocks exactly once -> linear pattern, NO swizzle, predicted 0
//     bank conflicts (R6/R7's 2-chunks-per-64B-row reads were intrinsically
//     2-way conflicted: identical 6.29M count under two different swizzles).
//     Skeleton = R5's proven best: 4-slot ring, 2 sub-phases per K-half,
//     vmcnt(8) once per half at issue->wait distance 4-5 phases.
// ---------------------------------------------------------------------------

typedef __attribute__((ext_vector_type(8))) short bf16x8;
typedef __attribute__((ext_vector_type(4))) float f32x4;
typedef __attribute__((ext_vector_type(16))) float f32x16;

__device__ __forceinline__ float b2f(short s) {
    union { unsigned u; float f; } x;
    x.u = ((unsigned)(unsigned short)s) << 16;
    return x.f;
}
__device__ __forceinline__ short f2b(float f) {
    union { float f; unsigned u; } x;
    x.f = f;
    unsigned r = (x.u + 0x7FFFu + ((x.u >> 16) & 1u)) >> 16;  // RNE
    return (short)r;
}

// ---- cast fp32 -> bf16 for two tensors in one launch ----------------------
__global__ __launch_bounds__(256) void cast2_f32_bf16(
    const float* __restrict__ in0, short* __restrict__ out0,
    const float* __restrict__ in1, short* __restrict__ out1, int n) {
    int i = (blockIdx.x * 256 + threadIdx.x) * 4;
    const float* in = in0;
    short* out = out0;
    if (i >= n) {
        i -= n;
        in = in1;
        out = out1;
    }
    float4 v = *(const float4*)(in + i);
    short4 o;
    o.x = f2b(v.x); o.y = f2b(v.y); o.z = f2b(v.z); o.w = f2b(v.w);
    *(short4*)(out + i) = o;
}

// ---- transpose + cast: W[K][N] fp32 -> Wt[N][K] bf16 ----------------------
__global__ __launch_bounds__(256) void transpose_cast2(
    const float* __restrict__ W0, short* __restrict__ Wt0,
    const float* __restrict__ W1, short* __restrict__ Wt1, int K, int N) {
    const float* W = blockIdx.z ? W1 : W0;
    short* Wt = blockIdx.z ? Wt1 : Wt0;
    __shared__ float tile[32][33];
    int tx = threadIdx.x;
    int ty = threadIdx.y;
    int bx = blockIdx.x * 32;
    int by = blockIdx.y * 32;
#pragma unroll
    for (int j = 0; j < 32; j += 8)
        tile[ty + j][tx] = W[(size_t)(by + ty + j) * N + bx + tx];
    __syncthreads();
#pragma unroll
    for (int j = 0; j < 32; j += 8)
        Wt[(size_t)(bx + ty + j) * K + by + tx] = f2b(tile[tx][ty + j]);
}

// ---- bf16 MFMA GEMM, 256x256 tile, 32x32x16, 4-slot K-half ring -----------
// 512 threads = 8 waves (2 row x 4 col), each wave owns 128x64 of C as a
// 4x2 grid of 32x32 frags (f32x16 acc). LDS: 4 ring slots x 32 KB; slot s
// holds K-half m (m&3==s), organized K-OCTET-MAJOR:
//   A: [oct 0..3][row 0..255][8 kcols]  (shorts: oct*2048 + row*8)
//   B: same at +8192 shorts.
// Frag read (mi, ks): lane reads the full 16B entry [2ks+kh][mi*32+l31] --
// 64 lanes cover two contiguous 512B blocks exactly once: linear, no
// conflicts, no swizzle. Staging: slot index == tid (forced by
// global_load_lds linear write), so source row = tid&255, oct = tid>>8;
// two A loads cover octs {0,1} and {2,3} (src +16 shorts).
// Per K-half, two sub-phases (R5 skeleton):
//   {6 ds_read (ks); 2 GLD (half m+3); s_barrier; lgkm0; 8 MFMA; s_barrier}
// vmcnt(8) once per half: 12 loads in flight, retires half m+1 (issued
// 4-5 phases earlier), never drains.
// Frag layouts 32x32x16 bf16: A/B: row|col = lane&31, k = (lane>>5)*8+j.
// C/D: col = lane&31, row = (reg&3) + 8*(reg>>2) + 4*(lane>>5)  [m74/m101].
#define BM 256
#define BN 256

#define GLD16(g, l)                                           \
    __builtin_amdgcn_global_load_lds(                         \
        (const __attribute__((address_space(1))) void*)(g),   \
        (__attribute__((address_space(3))) void*)(l), 16, 0, 0)

template <int OUT_BF16>
__global__ __launch_bounds__(512, 2) void gemm_bt(
    const short* __restrict__ A,    // [M][K] bf16
    const short* __restrict__ Bt,   // [N][K] bf16 (pre-transposed weight)
    const float* __restrict__ bias, // [N]
    void* __restrict__ Cout,        // [M][N] bf16 or fp32
    int M, int N, int K) {
    __shared__ __align__(16) short lds[65536];  // 128 KiB

    const int tid = threadIdx.x;

    // T1: XCD-chunked swizzle (nwg % 8 == 0 for all our shapes)
    const int NX = gridDim.x;
    const int nwg = NX * gridDim.y;
    int lin = blockIdx.y * NX + blockIdx.x;
    lin = (lin & 7) * (nwg >> 3) + (lin >> 3);
    const int bn = (lin % NX) * BN;
    const int bm = (lin / NX) * BM;

    const int lane = tid & 63;
    const int wave = tid >> 6;
    const int wr = wave >> 2;  // 0..1: 128-row block
    const int wc = wave & 3;   // 0..3: 64-col block
    const int l31 = lane & 31;
    const int kh = lane >> 5;
    // frag bases (shorts within a ring slot); +ks*4096, +mi*256 / +nj*256
    const int abase = kh * 2048 + (wr * 128 + l31) * 8;
    const int bbase = 8192 + kh * 2048 + (wc * 64 + l31) * 8;

    // staging: slot index == tid (linear LDS write); row = tid&255,
    // oct = tid>>8; A loads at src +0 (octs 0,1) and +16 (octs 2,3)
    const int srow = tid & 255;
    const int soct = (tid >> 8) << 3;
    const short* agp = A + (size_t)(bm + srow) * K + soct;
    const short* bgp = Bt + (size_t)(bn + srow) * K + soct;
    char* const lbase = (char*)lds;
    const int dst = tid * 16;

    f32x16 acc[4][2];
#pragma unroll
    for (int i = 0; i < 4; ++i)
#pragma unroll
        for (int j = 0; j < 2; ++j)
#pragma unroll
            for (int e = 0; e < 16; ++e) acc[i][j][e] = 0.f;

    // prologue: issue halves 0,1,2 (12 loads, oldest-first)
#pragma unroll
    for (int h = 0; h < 3; ++h) {
        const int kk = h << 5;
        GLD16(agp + kk, lbase + h * 32768 + dst);
        GLD16(agp + kk + 16, lbase + h * 32768 + 8192 + dst);
        GLD16(bgp + kk, lbase + h * 32768 + 16384 + dst);
        GLD16(bgp + kk + 16, lbase + h * 32768 + 24576 + dst);
    }
    asm volatile("s_waitcnt vmcnt(8)" ::: "memory");  // half 0 landed
    __builtin_amdgcn_s_barrier();

    const int NH = K >> 5;  // 32 K-halves
    for (int mm = 0; mm < NH; mm += 4) {
#pragma unroll
        for (int uu = 0; uu < 4; ++uu) {
            const int m = mm + uu;
            const int slot = uu;             // (mm+uu)&3 == uu
            const int wslot = (uu + 3) & 3;  // ring slot for half m+3
            // tail: re-issue last half's (L2-hot) addresses into the dead
            // slot to keep vmcnt counts uniform
            const int kis = ((m + 3 < NH) ? (m + 3) : (NH - 1)) << 5;
            const short* la = &lds[slot * 16384 + abase];
            const short* lb = &lds[slot * 16384 + bbase];
            bf16x8 af0[4], bf0[2], af1[4], bf1[2];
            // ---- sub-phase A (ks=0): 6 reads + A-prefetch + 8 MFMA ----
#pragma unroll
            for (int mi = 0; mi < 4; ++mi)
                af0[mi] = *(const bf16x8*)(la + mi * 256);
#pragma unroll
            for (int nj = 0; nj < 2; ++nj)
                bf0[nj] = *(const bf16x8*)(lb + nj * 256);
            GLD16(agp + kis, lbase + wslot * 32768 + dst);
            GLD16(agp + kis + 16, lbase + wslot * 32768 + 8192 + dst);
            __builtin_amdgcn_sched_barrier(0);
            __builtin_amdgcn_s_barrier();
            asm volatile("s_waitcnt lgkmcnt(0)" ::: "memory");
            __builtin_amdgcn_sched_barrier(0);
            __builtin_amdgcn_s_setprio(1);
#pragma unroll
            for (int mi = 0; mi < 4; ++mi)
#pragma unroll
                for (int nj = 0; nj < 2; ++nj)
                    acc[mi][nj] = __builtin_amdgcn_mfma_f32_32x32x16_bf16(
                        af0[mi], bf0[nj], acc[mi][nj], 0, 0, 0);
            __builtin_amdgcn_s_setprio(0);
            __builtin_amdgcn_s_barrier();
            // ---- sub-phase B (ks=1): 6 reads + B-prefetch + 8 MFMA ----
#pragma unroll
            for (int mi = 0; mi < 4; ++mi)
                af1[mi] = *(const bf16x8*)(la + 4096 + mi * 256);
#pragma unroll
            for (int nj = 0; nj < 2; ++nj)
                bf1[nj] = *(const bf16x8*)(lb + 4096 + nj * 256);
            GLD16(bgp + kis, lbase + wslot * 32768 + 16384 + dst);
            GLD16(bgp + kis + 16, lbase + wslot * 32768 + 24576 + dst);
            __builtin_amdgcn_sched_barrier(0);
            __builtin_amdgcn_s_barrier();
            asm volatile("s_waitcnt lgkmcnt(0)" ::: "memory");
            __builtin_amdgcn_sched_barrier(0);
            __builtin_amdgcn_s_setprio(1);
#pragma unroll
            for (int mi = 0; mi < 4; ++mi)
#pragma unroll
                for (int nj = 0; nj < 2; ++nj)
                    acc[mi][nj] = __builtin_amdgcn_mfma_f32_32x32x16_bf16(
                        af1[mi], bf1[nj], acc[mi][nj], 0, 0, 0);
            __builtin_amdgcn_s_setprio(0);
            // retire half m+1 (issued 4-5 phases ago); 8 stay in flight
            asm volatile("s_waitcnt vmcnt(8)" ::: "memory");
            __builtin_amdgcn_s_barrier();
        }
    }

    // epilogue: col = bn + wc*64 + nj*32 + l31,
    //           row = bm + wr*128 + mi*32 + (reg&3) + 8*(reg>>2) + 4*kh
    float bv[2];
#pragma unroll
    for (int nj = 0; nj < 2; ++nj) bv[nj] = bias[bn + wc * 64 + nj * 32 + l31];
#pragma unroll
    for (int mi = 0; mi < 4; ++mi) {
#pragma unroll
        for (int q = 0; q < 4; ++q) {
#pragma unroll
            for (int rr = 0; rr < 4; ++rr) {
                const int row = bm + wr * 128 + mi * 32 + rr + 8 * q + 4 * kh;
#pragma unroll
                for (int nj = 0; nj < 2; ++nj) {
                    const int col = bn + wc * 64 + nj * 32 + l31;
                    float v = acc[mi][nj][q * 4 + rr] + bv[nj];
                    if (OUT_BF16)
                        ((short*)Cout)[(size_t)row * N + col] = f2b(v);
                    else
                        ((float*)Cout)[(size_t)row * N + col] = v;
                }
            }
        }
    }
    // drain tail garbage-stages before LDS dealloc at wave exit
    asm volatile("s_waitcnt vmcnt(0)" ::: "memory");
}

// ---- attention over heads axis, one wave per position ---------------------
__global__ __launch_bounds__(256) void attn_kernel(
    const short* __restrict__ Q, const short* __restrict__ KV,
    short* __restrict__ VAL) {
    const int wave = threadIdx.x >> 6;
    const int lane = threadIdx.x & 63;
    const size_t p = (size_t)blockIdx.x * 4 + wave;
    const int dq = lane & 3;

    const bf16x8* qp = (const bf16x8*)(Q + p * 1024 + (size_t)lane * 16);
    bf16x8 q0 = qp[0], q1 = qp[1];
    float q[16];
#pragma unroll
    for (int j = 0; j < 8; ++j) {
        q[j] = b2f(q0[j]);
        q[8 + j] = b2f(q1[j]);
    }

    const short* kvb = KV + p * 2048;

    float s[16];
#pragma unroll
    for (int g = 0; g < 16; ++g) {
        const bf16x8* kp = (const bf16x8*)(kvb + g * 128 + dq * 16);
        bf16x8 k0 = kp[0], k1 = kp[1];
        float d = 0.f;
#pragma unroll
        for (int j = 0; j < 8; ++j) {
            d += q[j] * b2f(k0[j]);
            d += q[8 + j] * b2f(k1[j]);
        }
        s[g] = d;
    }
    float mx = -1e30f;
#pragma unroll
    for (int g = 0; g < 16; ++g) {
        s[g] += __shfl_xor(s[g], 1, 64);
        s[g] += __shfl_xor(s[g], 2, 64);
        s[g] *= 0.125f;
        mx = fmaxf(mx, s[g]);
    }
    float ssum = 0.f;
#pragma unroll
    for (int g = 0; g < 16; ++g) {
        s[g] = __expf(s[g] - mx);
        ssum += s[g];
    }
    const float inv = 1.0f / ssum;

    float vo[16];
#pragma unroll
    for (int j = 0; j < 16; ++j) vo[j] = 0.f;
#pragma unroll
    for (int g = 0; g < 16; ++g) {
        const float w = s[g] * inv;
        const bf16x8* vp = (const bf16x8*)(kvb + g * 128 + 64 + dq * 16);
        bf16x8 v0 = vp[0], v1 = vp[1];
#pragma unroll
        for (int j = 0; j < 8; ++j) {
            vo[j] += w * b2f(v0[j]);
            vo[8 + j] += w * b2f(v1[j]);
        }
    }

    bf16x8 o0, o1;
#pragma unroll
    for (int j = 0; j < 8; ++j) {
        o0[j] = f2b(vo[j]);
        o1[j] = f2b(vo[8 + j]);
    }
    bf16x8* op = (bf16x8*)(VAL + p * 1024 + (size_t)lane * 16);
    op[0] = o0;
    op[1] = o1;
}

// ---------------------------------------------------------------------------
extern "C" void kernel_launch(void* const* d_in, const int* in_sizes, int n_in,
                              void* d_out, int out_size, void* d_ws,
                              size_t ws_size, hipStream_t stream) {
    const float* x = (const float*)d_in[0];
    const float* y = (const float*)d_in[1];
    const float* Wkv = (const float*)d_in[2];
    const float* bkv = (const float*)d_in[3];
    const float* Wq = (const float*)d_in[4];
    const float* bq = (const float*)d_in[5];
    const float* Wo = (const float*)d_in[6];
    const float* bo = (const float*)d_in[7];
    float* out = (float*)d_out;

    const int D = 1024;
    const int M = 16384;  // B*L

    // workspace layout (142.6 MB total)
    char* ws = (char*)d_ws;
    short* Xb = (short*)(ws);                      // M*D bf16      (33.5 MB)
    short* Yb = (short*)(ws + 33554432);           // M*D bf16      (33.5 MB)
    short* Wkvt = (short*)(ws + 67108864);         // 2D*D bf16     (4 MB)
    short* Wqt = (short*)(ws + 71303168);          // D*D bf16      (2 MB)
    short* Wot = (short*)(ws + 73400320);          // D*D bf16      (2 MB)
    short* KV = (short*)(ws + 75497472);           // M*2D bf16     (67 MB)
    short* Q = Xb;    // Xb dead after kv GEMM
    short* VAL = Yb;  // Yb dead after q GEMM

    const int n = M * D;  // 16777216

    cast2_f32_bf16<<<2 * n / 1024, 256, 0, stream>>>(x, Xb, y, Yb, n);
    transpose_cast2<<<dim3(2 * D / 32, D / 32, 1), dim3(32, 8), 0, stream>>>(
        Wkv, Wkvt, (const float*)0, (short*)0, D, 2 * D);
    transpose_cast2<<<dim3(D / 32, D / 32, 2), dim3(32, 8), 0, stream>>>(
        Wq, Wqt, Wo, Wot, D, D);

    // kv = x @ Wkv + bkv   [16384 x 2048] bf16
    gemm_bt<1><<<dim3(2 * D / BN, M / BM), 512, 0, stream>>>(
        Xb, Wkvt, bkv, KV, M, 2 * D, D);
    // q = y @ Wq + bq      [16384 x 1024] bf16 (into Xb slot)
    gemm_bt<1><<<dim3(D / BN, M / BM), 512, 0, stream>>>(
        Yb, Wqt, bq, Q, M, D, D);
    // attention over heads -> VAL (into Yb slot)
    attn_kernel<<<M / 4, 256, 0, stream>>>(Q, KV, VAL);
    // out = val @ Wo + bo  [16384 x 1024] fp32
    gemm_bt<0><<<dim3(D / BN, M / BM), 512, 0, stream>>>(
        VAL, Wot, bo, out, M, D, D);
}